// Round 5
// baseline (119.414 us; speedup 1.0000x reference)
//
#include <hip/hip_runtime.h>
#include <math.h>

#define QUBITS 8
#define EMBED 512
#define FFN 2048
#define ROWS_PER_BLOCK 32
#define THREADS 256
#define NBLOCKS 2048   // 65536 rows / 32

using f32x4 = __attribute__((ext_vector_type(4))) float;

// R2 structure (best: 102.8us) with ONE change: strided row assignment.
// Block bid handles rows {bid, bid+2048, bid+4096, ...} so the machine-wide
// in-flight store frontier is one contiguous 16MB band sweeping the output —
// the same DRAM page-locality pattern as the 6.6 TB/s fill kernels.
__global__ __launch_bounds__(THREADS) void qff_kernel(
    const float* __restrict__ x, const float* __restrict__ params,
    const float* __restrict__ W, const float* __restrict__ b,
    float* __restrict__ out)
{
    __shared__ float z_lds[ROWS_PER_BLOCK][QUBITS];

    const int t = threadIdx.x;
    const int bid = blockIdx.x;

    // Stage z: thread t -> row-slot t/8, qubit t%8. Row index is strided.
    {
        const int r = t >> 3, q = t & 7;
        const long long row = (long long)bid + (long long)r * NBLOCKS;
        const float xv = x[row * EMBED + q];
        const float cp = cosf(params[q * 3]);   // params[q][0], row-major [8,3]
        z_lds[r][q] = cosf(xv) * cp;
    }
    __syncthreads();

    // Register-resident W rows + bias for this thread's 8 features.
    float w[2][4][QUBITS];
    float bias[2][4];
    #pragma unroll
    for (int k = 0; k < 2; ++k) {
        const int fbase = k * 1024 + t * 4;
        #pragma unroll
        for (int j = 0; j < 4; ++j) {
            const f32x4* wp = (const f32x4*)(W + (size_t)(fbase + j) * QUBITS);
            const f32x4 w0 = wp[0], w1 = wp[1];
            w[k][j][0] = w0.x; w[k][j][1] = w0.y; w[k][j][2] = w0.z; w[k][j][3] = w0.w;
            w[k][j][4] = w1.x; w[k][j][5] = w1.y; w[k][j][6] = w1.z; w[k][j][7] = w1.w;
            bias[k][j] = b[fbase + j];
        }
    }

    // Output pointer starts at row=bid, advances by NBLOCKS rows per iter.
    float* p = out + (long long)bid * FFN + (size_t)t * 4;
    const long long pstride = (long long)NBLOCKS * FFN;

    for (int r = 0; r < ROWS_PER_BLOCK; ++r) {
        float z[QUBITS];
        #pragma unroll
        for (int q = 0; q < QUBITS; ++q) z[q] = z_lds[r][q];  // LDS broadcast

        #pragma unroll
        for (int k = 0; k < 2; ++k) {
            float a[4];
            #pragma unroll
            for (int j = 0; j < 4; ++j) {
                float s = bias[k][j];
                #pragma unroll
                for (int q = 0; q < QUBITS; ++q) s = fmaf(z[q], w[k][j][q], s);
                a[j] = s;
            }
            f32x4 acc;
            acc.x = a[0]; acc.y = a[1]; acc.z = a[2]; acc.w = a[3];
            __builtin_nontemporal_store(acc, (f32x4*)(p + k * 1024));
        }
        p += pstride;
    }
}

extern "C" void kernel_launch(void* const* d_in, const int* in_sizes, int n_in,
                              void* d_out, int out_size, void* d_ws, size_t ws_size,
                              hipStream_t stream) {
    const float* x      = (const float*)d_in[0];
    const float* params = (const float*)d_in[1];
    const float* W      = (const float*)d_in[2];
    const float* b      = (const float*)d_in[3];
    float* out = (float*)d_out;

    qff_kernel<<<NBLOCKS, THREADS, 0, stream>>>(x, params, W, b, out);
}

// Round 6
// 107.582 us; speedup vs baseline: 1.1100x; 1.1100x over previous
//
#include <hip/hip_runtime.h>
#include <math.h>

#define QUBITS 8
#define EMBED 512
#define FFN 2048
#define ROWS_PER_BLOCK 32
#define THREADS 256

using f32x4 = __attribute__((ext_vector_type(4))) float;

// ---------- Pass 1: z[row][q] = cos(x[row,q]) * cos(params[q][0]) ----------
// 2 threads per row; each reads 16B of x (cols 0-3 or 4-7), writes 16B of z.
// Gets ALL scattered x HBM reads out of the way in one short dispatch so the
// big store kernel sees a pure-write DRAM stream (like the 6.6 TB/s fills).
__global__ __launch_bounds__(THREADS) void zprep_kernel(
    const float* __restrict__ x, const float* __restrict__ params,
    float* __restrict__ z, long long rows)
{
    const long long tid = (long long)blockIdx.x * THREADS + threadIdx.x;
    const long long row = tid >> 1;
    if (row >= rows) return;
    const int half = (int)(tid & 1);

    float cp[4];
    #pragma unroll
    for (int j = 0; j < 4; ++j) cp[j] = cosf(params[(half * 4 + j) * 3]);

    const f32x4 xv = *(const f32x4*)(x + row * EMBED + half * 4);
    f32x4 zv;
    zv.x = cosf(xv.x) * cp[0];
    zv.y = cosf(xv.y) * cp[1];
    zv.z = cosf(xv.z) * cp[2];
    zv.w = cosf(xv.w) * cp[3];
    *(f32x4*)(z + row * QUBITS + half * 4) = zv;
}

// ---------- Pass 2: out[row][f] = sum_q z[row][q]*W[f][q] + b[f] ----------
// R2 structure (best: 102.8us): 32 rows/block, NT stores, W/bias in regs.
// Staging is now a single coalesced 1KB contiguous read of precomputed z
// (L2/L3-warm), instead of 32 scattered HBM lines + cosf chain.
__global__ __launch_bounds__(THREADS) void qff_store_kernel(
    const float* __restrict__ z, const float* __restrict__ W,
    const float* __restrict__ b, float* __restrict__ out)
{
    __shared__ float z_lds[ROWS_PER_BLOCK * QUBITS];

    const int t = threadIdx.x;
    const long long row0 = (long long)blockIdx.x * ROWS_PER_BLOCK;

    // 1KB contiguous coalesced copy: z[row0*8 .. row0*8+256) -> LDS.
    z_lds[t] = z[row0 * QUBITS + t];
    __syncthreads();

    float w[2][4][QUBITS];
    float bias[2][4];
    #pragma unroll
    for (int k = 0; k < 2; ++k) {
        const int fbase = k * 1024 + t * 4;
        #pragma unroll
        for (int j = 0; j < 4; ++j) {
            const f32x4* wp = (const f32x4*)(W + (size_t)(fbase + j) * QUBITS);
            const f32x4 w0 = wp[0], w1 = wp[1];
            w[k][j][0] = w0.x; w[k][j][1] = w0.y; w[k][j][2] = w0.z; w[k][j][3] = w0.w;
            w[k][j][4] = w1.x; w[k][j][5] = w1.y; w[k][j][6] = w1.z; w[k][j][7] = w1.w;
            bias[k][j] = b[fbase + j];
        }
    }

    float* p = out + row0 * FFN + (size_t)t * 4;

    for (int r = 0; r < ROWS_PER_BLOCK; ++r) {
        float zv[QUBITS];
        #pragma unroll
        for (int q = 0; q < QUBITS; ++q) zv[q] = z_lds[r * QUBITS + q];  // broadcast

        #pragma unroll
        for (int k = 0; k < 2; ++k) {
            float a[4];
            #pragma unroll
            for (int j = 0; j < 4; ++j) {
                float s = bias[k][j];
                #pragma unroll
                for (int q = 0; q < QUBITS; ++q) s = fmaf(zv[q], w[k][j][q], s);
                a[j] = s;
            }
            f32x4 acc;
            acc.x = a[0]; acc.y = a[1]; acc.z = a[2]; acc.w = a[3];
            __builtin_nontemporal_store(acc, (f32x4*)(p + k * 1024));
        }
        p += FFN;
    }
}

// ---------- Fallback: fused R2 kernel (used only if ws too small) ----------
__global__ __launch_bounds__(THREADS) void qff_fused_kernel(
    const float* __restrict__ x, const float* __restrict__ params,
    const float* __restrict__ W, const float* __restrict__ b,
    float* __restrict__ out)
{
    __shared__ float z_lds[ROWS_PER_BLOCK][QUBITS];

    const int t = threadIdx.x;
    const long long row0 = (long long)blockIdx.x * ROWS_PER_BLOCK;
    {
        const int r = t >> 3, q = t & 7;
        const float xv = x[(row0 + r) * EMBED + q];
        z_lds[r][q] = cosf(xv) * cosf(params[q * 3]);
    }
    __syncthreads();

    float w[2][4][QUBITS];
    float bias[2][4];
    #pragma unroll
    for (int k = 0; k < 2; ++k) {
        const int fbase = k * 1024 + t * 4;
        #pragma unroll
        for (int j = 0; j < 4; ++j) {
            const f32x4* wp = (const f32x4*)(W + (size_t)(fbase + j) * QUBITS);
            const f32x4 w0 = wp[0], w1 = wp[1];
            w[k][j][0] = w0.x; w[k][j][1] = w0.y; w[k][j][2] = w0.z; w[k][j][3] = w0.w;
            w[k][j][4] = w1.x; w[k][j][5] = w1.y; w[k][j][6] = w1.z; w[k][j][7] = w1.w;
            bias[k][j] = b[fbase + j];
        }
    }

    float* p = out + row0 * FFN + (size_t)t * 4;
    for (int r = 0; r < ROWS_PER_BLOCK; ++r) {
        float zv[QUBITS];
        #pragma unroll
        for (int q = 0; q < QUBITS; ++q) zv[q] = z_lds[r][q];
        #pragma unroll
        for (int k = 0; k < 2; ++k) {
            float a[4];
            #pragma unroll
            for (int j = 0; j < 4; ++j) {
                float s = bias[k][j];
                #pragma unroll
                for (int q = 0; q < QUBITS; ++q) s = fmaf(zv[q], w[k][j][q], s);
                a[j] = s;
            }
            f32x4 acc;
            acc.x = a[0]; acc.y = a[1]; acc.z = a[2]; acc.w = a[3];
            __builtin_nontemporal_store(acc, (f32x4*)(p + k * 1024));
        }
        p += FFN;
    }
}

extern "C" void kernel_launch(void* const* d_in, const int* in_sizes, int n_in,
                              void* d_out, int out_size, void* d_ws, size_t ws_size,
                              hipStream_t stream) {
    const float* x      = (const float*)d_in[0];
    const float* params = (const float*)d_in[1];
    const float* W      = (const float*)d_in[2];
    const float* b      = (const float*)d_in[3];
    float* out = (float*)d_out;

    const long long rows = (long long)in_sizes[0] / EMBED;   // 65536
    const size_t zbytes = (size_t)rows * QUBITS * sizeof(float);  // 2 MiB

    if (ws_size >= zbytes) {
        float* z = (float*)d_ws;
        const int grid1 = (int)((rows * 2 + THREADS - 1) / THREADS);  // 512
        zprep_kernel<<<grid1, THREADS, 0, stream>>>(x, params, z, rows);
        const int grid2 = (int)(rows / ROWS_PER_BLOCK);               // 2048
        qff_store_kernel<<<grid2, THREADS, 0, stream>>>(z, W, b, out);
    } else {
        const int grid = (int)(rows / ROWS_PER_BLOCK);
        qff_fused_kernel<<<grid, THREADS, 0, stream>>>(x, params, W, b, out);
    }
}